// Round 5
// baseline (304.817 us; speedup 1.0000x reference)
//
#include <hip/hip_runtime.h>
#include <cstdint>
#include <cstddef>

typedef unsigned short u16;
typedef __attribute__((ext_vector_type(8))) __bf16 bf16x8;
typedef __attribute__((ext_vector_type(4))) float f32x4;
typedef __attribute__((ext_vector_type(16))) float f32x16;
typedef __attribute__((ext_vector_type(2))) uint32_t u32x2;
typedef __attribute__((ext_vector_type(4))) float float4v;

#define BATCH 4
#define S_LEN 2048
#define DMODEL 1024
#define NHEAD 16
#define HDIM 64
#define MROWS (BATCH * S_LEN)   // 8192
#define LOG2E 1.4426950408889634f
#define SC_L (0.125f * LOG2E)   // 1/sqrt(64) * log2(e)

__device__ __forceinline__ u16 f2bf(float f) {
  uint32_t u = __float_as_uint(f);
  u += 0x7fffu + ((u >> 16) & 1u);   // RNE
  return (u16)(u >> 16);
}

#if __has_builtin(__builtin_amdgcn_cvt_pk_bf16_f32)
__device__ __forceinline__ uint32_t packbf2(float a, float b) {
  auto t = __builtin_amdgcn_cvt_pk_bf16_f32(a, b);
  uint32_t u;
  __builtin_memcpy(&u, &t, 4);
  return u;
}
#else
__device__ __forceinline__ uint32_t packbf2(float a, float b) {
  uint32_t ua = __float_as_uint(a) + 0x8000u;
  uint32_t ub = __float_as_uint(b) + 0x8000u;
  return (ub & 0xFFFF0000u) | (ua >> 16);
}
#endif

#if __has_builtin(__builtin_amdgcn_exp2f)
#define EXP2(x) __builtin_amdgcn_exp2f(x)
#else
#define EXP2(x) exp2f(x)
#endif

typedef __attribute__((address_space(1))) void gvoid_t;
typedef __attribute__((address_space(3))) void svoid_t;
__device__ __forceinline__ void gl_lds16(const void* g, void* s) {
  __builtin_amdgcn_global_load_lds((gvoid_t*)g, (svoid_t*)s, 16, 0, 0);
}

// ---------------- prep: x fp32->bf16 (4/thread) + mask*log2e ----------------
__global__ __launch_bounds__(256) void prep_kernel(const float4v* __restrict__ x,
                                                   u32x2* __restrict__ xb,
                                                   const float4v* __restrict__ mask,
                                                   float4v* __restrict__ mL,
                                                   int nx4, int nm4) {
  int i = blockIdx.x * blockDim.x + threadIdx.x;
  if (i < nx4) {
    float4v v = x[i];
    u32x2 o;
    o.x = packbf2(v.x, v.y);
    o.y = packbf2(v.z, v.w);
    xb[i] = o;
  } else {
    int j = i - nx4;
    if (j < nm4) {
      float4v m = mask[j];
      mL[j] = m * LOG2E;
    }
  }
}

// ---------------- W [k][n] fp32 -> Wt [n][k] bf16, all 4 weights ----------------
__global__ __launch_bounds__(256) void tcvt_kernel(const float* __restrict__ W0,
                                                   const float* __restrict__ W1,
                                                   const float* __restrict__ W2,
                                                   const float* __restrict__ W3,
                                                   u16* __restrict__ Wall) {
  __shared__ float tile[32][33];
  const int z = blockIdx.z;
  const float* W = (z == 0) ? W0 : (z == 1) ? W1 : (z == 2) ? W2 : W3;
  u16* Wt = Wall + (size_t)z * DMODEL * DMODEL;
  const int n0 = blockIdx.x * 32, k0 = blockIdx.y * 32;
  const int x = threadIdx.x, y = threadIdx.y;   // (32,8)
  for (int yy = y; yy < 32; yy += 8)
    tile[yy][x] = W[(size_t)(k0 + yy) * DMODEL + n0 + x];
  __syncthreads();
  for (int yy = y; yy < 32; yy += 8)
    Wt[(size_t)(n0 + yy) * DMODEL + k0 + x] = f2bf(tile[x][yy]);
}

// ---------------- m97-style GEMM ----------------
// MODE 0: fused QKV, N=3072. seg 0/1 -> Q/K head layout [B,NH,S,HD];
//         seg 2 -> V TRANSPOSED [B,NH,HD,S] via per-wave LDS bounce (b128 stores).
// MODE 1: N=1024, fp32 out row-major.
template <int MODE>
__global__ __launch_bounds__(256) void gemm128(const u16* __restrict__ A,
                                               const u16* __restrict__ Bt,
                                               const float* __restrict__ b0,
                                               const float* __restrict__ b1,
                                               const float* __restrict__ b2,
                                               void* __restrict__ o0,
                                               void* __restrict__ o1,
                                               void* __restrict__ o2) {
  __shared__ u16 As[128 * 32];
  __shared__ u16 Bs[128 * 32];
  const int tid = threadIdx.x;
  const int wid = tid >> 6;
  const int lane = tid & 63;
  const int l16 = lane & 15;
  const int g4 = lane >> 4;
  const int m0 = blockIdx.x * 128;
  const int n0 = blockIdx.y * 128;
  const int wm = (wid & 1) * 64;
  const int wn = (wid >> 1) * 64;

  const int srow = tid >> 2;
  const int sk = (tid & 3) * 8;
  const u16* gA = A + (size_t)(m0 + srow) * DMODEL + sk;
  const u16* gB = Bt + (size_t)(n0 + srow) * DMODEL + sk;
  char* sA = (char*)As + wid * 1024;
  char* sB = (char*)Bs + wid * 1024;

  f32x4 acc[4][4];
#pragma unroll
  for (int i = 0; i < 4; ++i)
#pragma unroll
    for (int j = 0; j < 4; ++j) acc[i][j] = (f32x4){0.f, 0.f, 0.f, 0.f};

  for (int k0 = 0; k0 < DMODEL; k0 += 32) {
    __syncthreads();
    gl_lds16(gA + k0, sA);
    gl_lds16(gA + (size_t)64 * DMODEL + k0, sA + 4096);
    gl_lds16(gB + k0, sB);
    gl_lds16(gB + (size_t)64 * DMODEL + k0, sB + 4096);
    __syncthreads();

    bf16x8 af[4], bfr[4];
#pragma unroll
    for (int i = 0; i < 4; ++i)
      af[i] = *(const bf16x8*)(As + (wm + i * 16 + l16) * 32 + g4 * 8);
#pragma unroll
    for (int j = 0; j < 4; ++j)
      bfr[j] = *(const bf16x8*)(Bs + (wn + j * 16 + l16) * 32 + g4 * 8);
#pragma unroll
    for (int i = 0; i < 4; ++i)
#pragma unroll
      for (int j = 0; j < 4; ++j)
        acc[i][j] = __builtin_amdgcn_mfma_f32_16x16x32_bf16(af[i], bfr[j],
                                                            acc[i][j], 0, 0, 0);
  }

  const int seg = n0 >> 10;   // wave-uniform
  const float* bp = (MODE == 1 || seg == 0) ? b0 : (seg == 1 ? b1 : b2);
  void* op = (MODE == 1 || seg == 0) ? o0 : (seg == 1 ? o1 : o2);

  if (MODE == 0 && seg == 2) {
    // V transposed via per-wave LDS bounce: rows=n(16/pass, stride 72), cols=m(64)
    __syncthreads();   // all waves done reading As/Bs staging data
    u16* Tr = ((wid & 2) ? Bs : As) + (wid & 1) * 1152;   // 16*72 u16 region
#pragma unroll
    for (int j = 0; j < 4; ++j) {
      const int cseg = (n0 + wn + j * 16 + l16) & 1023;
      const float bval = bp[cseg];
#pragma unroll
      for (int i = 0; i < 4; ++i) {
        u32x2 w;
        w.x = packbf2(acc[i][j][0] + bval, acc[i][j][1] + bval);
        w.y = packbf2(acc[i][j][2] + bval, acc[i][j][3] + bval);
        *(u32x2*)(Tr + l16 * 72 + i * 16 + g4 * 4) = w;   // ds_write_b64
      }
      // same-wave DS ordering: reads below see this wave's writes above
#pragma unroll
      for (int rr = 0; rr < 2; ++rr) {
        const int n_loc = rr * 8 + (lane >> 3);
        const int m_loc = (lane & 7) * 8;
        bf16x8 v = *(const bf16x8*)(Tr + n_loc * 72 + m_loc);
        const int cs2 = (n0 + wn + j * 16 + n_loc) & 1023;
        const int h = cs2 >> 6, d = cs2 & 63;
        const int mg = m0 + wm + m_loc;
        const int b = mg >> 11, s = mg & (S_LEN - 1);
        *(bf16x8*)((u16*)op + (((size_t)(b * NHEAD + h) * HDIM + d) << 11) + s) = v;
      }
    }
    return;
  }

#pragma unroll
  for (int i = 0; i < 4; ++i) {
#pragma unroll
    for (int j = 0; j < 4; ++j) {
      const int coll = n0 + wn + j * 16 + l16;
      const int cseg = coll & 1023;
      const float bval = bp[cseg];
#pragma unroll
      for (int r = 0; r < 4; ++r) {
        const int rowg = m0 + wm + i * 16 + g4 * 4 + r;
        const float v = acc[i][j][r] + bval;
        if (MODE == 0) {
          const int b = rowg >> 11, s = rowg & (S_LEN - 1);
          const int h = cseg >> 6, d = cseg & (HDIM - 1);
          ((u16*)op)[((size_t)((b * NHEAD + h) * S_LEN + s) << 6) + d] = f2bf(v);
        } else {
          ((float*)op)[(size_t)rowg * DMODEL + cseg] = v;
        }
      }
    }
  }
}

// ---------------- flash attention v5 ----------------
// 32 q/wave, 128-key tiles, register-P (pi-permuted V), VALU-accumulated l.
// Block = 4 waves = 128 q; grid (S/128, B*NH) XCD-swizzled.
// launch_bounds(256,4): target 4 waves/SIMD for latency hiding.
__global__ __launch_bounds__(256, 4) void attn5_kernel(const u16* __restrict__ Q,
                                                       const u16* __restrict__ K,
                                                       const u16* __restrict__ Vt,
                                                       const float* __restrict__ maskL,
                                                       u16* __restrict__ ctx) {
  __shared__ u16 Ks[128 * 72];   // [key][d]
  __shared__ u16 Vs[64 * 136];   // [d][key'] (pi-permuted keys)

  const int tid = threadIdx.x;
  const int wid = tid >> 6;
  const int lane = tid & 63;
  const int l32 = lane & 31;
  const int hi = lane >> 5;
  // XCD swizzle: 1024 blocks; 128 consecutive nf per XCD = 8 full heads.
  const int flat = blockIdx.y * gridDim.x + blockIdx.x;
  const int nf = (flat & 7) * 128 + (flat >> 3);
  const int bx = nf & 15;
  const int bh = nf >> 4;
  const int b = bh >> 4;
  const int h = bh & 15;
  const int q0w = bx * 128 + wid * 32;

  // Q B-fragments: n=q=l32, k = c*16 + hi*8 + j
  const u16* Qp = Q + ((size_t)bh * S_LEN + q0w + l32) * HDIM;
  bf16x8 aq[4];
#pragma unroll
  for (int c = 0; c < 4; ++c)
    aq[c] = *(const bf16x8*)(Qp + c * 16 + hi * 8);

  const f32x16 z16 = {};
  f32x16 oacc[2] = {};   // [dh]
  float lsum = 0.f;

  // staging maps (256 threads)
  const int krow = tid >> 1;            // 0..127
  const int kcol = (tid & 1) * 32;
  const int vd = tid >> 2;              // 0..63
  const int vc = (tid & 3) * 32;
  const u16* Kg = K + (size_t)bh * S_LEN * HDIM + (size_t)krow * HDIM + kcol;
  const u16* Vg = Vt + (size_t)bh * HDIM * S_LEN + (size_t)vd * S_LEN + vc;
  const float* mrow = maskL + (size_t)b * S_LEN;

  for (int kt = 0; kt < S_LEN; kt += 128) {
    bf16x8 kv[4];
    union { bf16x8 v; uint32_t u[4]; } vv[4];
#pragma unroll
    for (int r = 0; r < 4; ++r) {
      kv[r] = *(const bf16x8*)(Kg + (size_t)kt * HDIM + r * 8);
      vv[r].v = *(const bf16x8*)(Vg + kt + r * 8);
    }
    __syncthreads();   // prev-iter readers done
#pragma unroll
    for (int r = 0; r < 4; ++r) {
      *(bf16x8*)(Ks + krow * 72 + kcol + r * 8) = kv[r];
      const int kb = vc + r * 8;
      const int vkb = ((kb >> 4) << 4) + (((kb >> 3) & 1) << 2);   // pi base
      *(u32x2*)(Vs + vd * 136 + vkb) = (u32x2){vv[r].u[0], vv[r].u[1]};
      *(u32x2*)(Vs + vd * 136 + vkb + 8) = (u32x2){vv[r].u[2], vv[r].u[3]};
    }
    __syncthreads();

    union PU { uint32_t u[8]; bf16x8 v[2]; } P[4];
#pragma unroll
    for (int T = 0; T < 4; ++T) {
      bf16x8 kf[4];
#pragma unroll
      for (int c = 0; c < 4; ++c)
        kf[c] = *(const bf16x8*)(Ks + (T * 32 + l32) * 72 + c * 16 + hi * 8);
      f32x16 s = __builtin_amdgcn_mfma_f32_32x32x16_bf16(kf[0], aq[0], z16, 0, 0, 0);
#pragma unroll
      for (int c = 1; c < 4; ++c)
        s = __builtin_amdgcn_mfma_f32_32x32x16_bf16(kf[c], aq[c], s, 0, 0, 0);
#pragma unroll
      for (int tq = 0; tq < 4; ++tq) {
        f32x4 m4 = *(const f32x4*)(mrow + kt + T * 32 + tq * 8 + hi * 4);
        float p0 = EXP2(fmaf(s[tq * 4 + 0], SC_L, m4[0]));
        float p1 = EXP2(fmaf(s[tq * 4 + 1], SC_L, m4[1]));
        float p2 = EXP2(fmaf(s[tq * 4 + 2], SC_L, m4[2]));
        float p3 = EXP2(fmaf(s[tq * 4 + 3], SC_L, m4[3]));
        lsum += (p0 + p1) + (p2 + p3);
        P[T].u[tq * 2] = packbf2(p0, p1);
        P[T].u[tq * 2 + 1] = packbf2(p2, p3);
      }
    }

    // PV: A = register P fragments, B = pi-permuted V from LDS
#pragma unroll
    for (int c = 0; c < 8; ++c) {
      bf16x8 pf = P[c >> 1].v[c & 1];
      bf16x8 vf0 = *(const bf16x8*)(Vs + l32 * 136 + c * 16 + hi * 8);
      bf16x8 vf1 = *(const bf16x8*)(Vs + (32 + l32) * 136 + c * 16 + hi * 8);
      oacc[0] = __builtin_amdgcn_mfma_f32_32x32x16_bf16(pf, vf0, oacc[0], 0, 0, 0);
      oacc[1] = __builtin_amdgcn_mfma_f32_32x32x16_bf16(pf, vf1, oacc[1], 0, 0, 0);
    }
  }

  // epilogue: combine l halves, broadcast to row space, store ctx [B,S,NH,HD]
  const float lc = lsum + __shfl_xor(lsum, 32);
#pragma unroll
  for (int reg = 0; reg < 16; ++reg) {
    const int qt = (reg & 3) + 8 * (reg >> 2) + 4 * hi;
    const float inv = 1.0f / __shfl(lc, qt, 32);
    const int q = q0w + qt;
    u16* cp = ctx + ((size_t)(b * S_LEN + q) * NHEAD + h) * HDIM;
    cp[l32] = f2bf(oacc[0][reg] * inv);
    cp[32 + l32] = f2bf(oacc[1][reg] * inv);
  }
}

extern "C" void kernel_launch(void* const* d_in, const int* in_sizes, int n_in,
                              void* d_out, int out_size, void* d_ws, size_t ws_size,
                              hipStream_t stream) {
  const float* x = (const float*)d_in[0];
  const float* mask = (const float*)d_in[1];
  const float* Wq = (const float*)d_in[2];
  const float* bq = (const float*)d_in[3];
  const float* Wk = (const float*)d_in[4];
  const float* bk = (const float*)d_in[5];
  const float* Wv = (const float*)d_in[6];
  const float* bv = (const float*)d_in[7];
  const float* Wo = (const float*)d_in[8];
  const float* bo = (const float*)d_in[9];
  float* out = (float*)d_out;

  char* ws = (char*)d_ws;
  size_t off = 0;
  u16* xb = (u16*)(ws + off);    off += (size_t)MROWS * DMODEL * 2;
  u16* wall = (u16*)(ws + off);  off += (size_t)4 * DMODEL * DMODEL * 2;
  u16* Qh = (u16*)(ws + off);    off += (size_t)MROWS * DMODEL * 2;   // [B,NH,S,HD]
  u16* Kh = (u16*)(ws + off);    off += (size_t)MROWS * DMODEL * 2;
  u16* Vtb = (u16*)(ws + off);   off += (size_t)MROWS * DMODEL * 2;   // [B,NH,HD,S]
  u16* ctxb = (u16*)(ws + off);  off += (size_t)MROWS * DMODEL * 2;   // [B,S,D]
  float* mL = (float*)(ws + off); off += (size_t)BATCH * S_LEN * 4;
  (void)ws_size; (void)in_sizes; (void)n_in; (void)out_size;

  const int nx4 = MROWS * DMODEL / 4;
  const int nm4 = BATCH * S_LEN / 4;
  prep_kernel<<<dim3((nx4 + nm4 + 255) / 256), dim3(256), 0, stream>>>(
      (const float4v*)x, (u32x2*)xb, (const float4v*)mask, (float4v*)mL, nx4, nm4);
  tcvt_kernel<<<dim3(32, 32, 4), dim3(32, 8), 0, stream>>>(Wq, Wk, Wv, Wo, wall);

  // fused QKV: N = 3072; V written transposed via LDS bounce
  gemm128<0><<<dim3(MROWS / 128, 3 * DMODEL / 128), dim3(256), 0, stream>>>(
      xb, wall, bq, bk, bv, (void*)Qh, (void*)Kh, (void*)Vtb);

  attn5_kernel<<<dim3(S_LEN / 128, BATCH * NHEAD), dim3(256), 0, stream>>>(Qh, Kh, Vtb, mL, ctxb);

  gemm128<1><<<dim3(MROWS / 128, DMODEL / 128), dim3(256), 0, stream>>>(
      ctxb, wall + (size_t)3 * DMODEL * DMODEL, bo, bo, bo, (void*)out, (void*)out, (void*)out);
}